// Round 3
// baseline (444.064 us; speedup 1.0000x reference)
//
#include <hip/hip_runtime.h>
#include <hip/hip_bf16.h>

// ---------------------------------------------------------------------------
// RETAIN forward, MI355X gfx950.
// T=64, B=64, D_IN=4096, E=128, HA=HB=128, D_OUT=4096
// R3: k_recur — amdgpu_waves_per_eu(2,2) to unlock 256 VGPRs (R2's VGPR=128
//     forced per-step rematerialization of W_hh fragments from global);
//     W_beta/w_alpha fragments moved to LDS; prefetch regs dropped (loads at
//     step top cover L2 latency under the MFMA phase). Packed bf16 converts.
// ---------------------------------------------------------------------------

typedef __attribute__((ext_vector_type(8))) short short8;
typedef __attribute__((ext_vector_type(4))) float f32x4;

#define MFMA16(a, b, c) __builtin_amdgcn_mfma_f32_16x16x32_bf16((a), (b), (c), 0, 0, 0)

__device__ __forceinline__ unsigned short f2bf(float f) {
  unsigned int u = __float_as_uint(f);
  u += 0x7fffu + ((u >> 16) & 1u);   // RNE (inputs are never NaN here)
  return (unsigned short)(u >> 16);
}
__device__ __forceinline__ unsigned pkbf(float a, float b) {  // v_cvt_pk_bf16_f32
  __hip_bfloat162 t = __float22bfloat162_rn(float2{a, b});
  return *reinterpret_cast<unsigned*>(&t);
}
__device__ __forceinline__ float sigm(float x) { return 1.0f / (1.0f + __expf(-x)); }
__device__ __forceinline__ float tanh_f(float x) {
  // one-sided clamp: e overflows only for x < -44 (tanh == -1 there)
  float e = __expf(-2.0f * fmaxf(x, -44.0f));
  return (1.0f - e) / (1.0f + e);
}

// ---- workspace layout (byte offsets), total ~34.4 MiB ----
#define OFF_PART   0u           // 8 * 524288 f32   emb K-split partials
#define OFF_EMB    16777216u    // 524288 f32       emb
#define OFF_GI     18874368u    // 4096*768 f32     gi concat (a: 0..383, b: 384..767), includes b_ih
#define OFF_EMBBF  31457280u    // 524288 bf16
#define OFF_CBF    32505856u    // 524288 bf16      c (T*B, 128)
#define OFF_WEMB   33554432u    // 524288 bf16
#define OFF_WOUT   34603008u    // 524288 bf16
#define OFF_WHHA   35651584u    // 49152 bf16
#define OFF_WHHB   35749888u    // 49152 bf16
#define OFF_WIH    35848192u    // 98304 bf16       [W_ih_a ; W_ih_b]
#define OFF_WBETA  36044800u    // 16384 bf16       0.5 * W_beta
#define OFF_WALPHA 36077568u    // 2048  bf16       16x128 tile, row0 = 0.5*w_alpha

// ---------------------------------------------------------------------------
// pair-wise weight cast (all section boundaries are even)
__global__ void k_prep(const float* W_emb, const float* W_out,
                       const float* W_hh_a, const float* W_hh_b,
                       const float* W_ih_a, const float* W_ih_b,
                       const float* W_beta, const float* w_alpha,
                       unsigned* wemb, unsigned* wout,
                       unsigned* whha, unsigned* whhb,
                       unsigned* wih, unsigned* wbeta,
                       unsigned* walpha) {
  const unsigned total = 631808u;  // element-pairs
  for (unsigned idx = blockIdx.x * 256u + threadIdx.x; idx < total;
       idx += gridDim.x * 256u) {
    unsigned i = idx;
    if (i < 262144u) { float2 v = ((const float2*)W_emb)[i]; wemb[i] = pkbf(v.x, v.y); continue; }
    i -= 262144u;
    if (i < 262144u) { float2 v = ((const float2*)W_out)[i]; wout[i] = pkbf(v.x, v.y); continue; }
    i -= 262144u;
    if (i < 24576u) { float2 v = ((const float2*)W_hh_a)[i]; whha[i] = pkbf(v.x, v.y); continue; }
    i -= 24576u;
    if (i < 24576u) { float2 v = ((const float2*)W_hh_b)[i]; whhb[i] = pkbf(v.x, v.y); continue; }
    i -= 24576u;
    if (i < 24576u) { float2 v = ((const float2*)W_ih_a)[i]; wih[i] = pkbf(v.x, v.y); continue; }
    i -= 24576u;
    if (i < 24576u) { float2 v = ((const float2*)W_ih_b)[i]; wih[24576u + i] = pkbf(v.x, v.y); continue; }
    i -= 24576u;
    if (i < 8192u) { float2 v = ((const float2*)W_beta)[i]; wbeta[i] = pkbf(0.5f * v.x, 0.5f * v.y); continue; }
    i -= 8192u;
    { // walpha tile: 16 x 128, row 0 = 0.5*w_alpha, rest 0
      unsigned e = i * 2, k = e & 127u;
      if ((e >> 7) == 0) { float2 v = ((const float2*)w_alpha)[k >> 1]; walpha[i] = pkbf(0.5f * v.x, 0.5f * v.y); }
      else walpha[i] = 0u;
    }
  }
}

// ---------------------------------------------------------------------------
// emb partials: 256 blocks = 32 m-tiles(128) x 8 K-chunks(512). N = 128 (full E).
__global__ __launch_bounds__(256) void k_emb_gemm(const float* __restrict__ x,
                                                  const unsigned short* __restrict__ wemb,
                                                  float* __restrict__ part) {
  const int mt = blockIdx.x >> 3, kc = blockIdx.x & 7;
  const int w = threadIdx.x >> 6, lane = threadIdx.x & 63, q = lane >> 4, ln = lane & 15;
  const f32x4 zero = {0.f, 0.f, 0.f, 0.f};
  f32x4 acc[2][8];
#pragma unroll
  for (int a = 0; a < 2; ++a)
#pragma unroll
    for (int b = 0; b < 8; ++b) acc[a][b] = zero;

  const float* xA = x + (size_t)(mt * 128 + (2 * w) * 16 + ln) * 4096 + kc * 512 + q * 8;
  const float* xB = xA + (size_t)16 * 4096;

  for (int kk = 0; kk < 16; ++kk) {
    const int ko = kk * 32;
    float4 u0 = *(const float4*)(xA + ko);
    float4 u1 = *(const float4*)(xA + ko + 4);
    float4 v0 = *(const float4*)(xB + ko);
    float4 v1 = *(const float4*)(xB + ko + 4);
    union { short8 v; unsigned u[4]; } a0, a1;
    a0.u[0] = pkbf(u0.x, u0.y); a0.u[1] = pkbf(u0.z, u0.w);
    a0.u[2] = pkbf(u1.x, u1.y); a0.u[3] = pkbf(u1.z, u1.w);
    a1.u[0] = pkbf(v0.x, v0.y); a1.u[1] = pkbf(v0.z, v0.w);
    a1.u[2] = pkbf(v1.x, v1.y); a1.u[3] = pkbf(v1.z, v1.w);
#pragma unroll
    for (int nt = 0; nt < 8; ++nt) {
      short8 b = *(const short8*)(wemb + (size_t)(nt * 16 + ln) * 4096 + kc * 512 + ko + q * 8);
      acc[0][nt] = MFMA16(a0.v, b, acc[0][nt]);
      acc[1][nt] = MFMA16(a1.v, b, acc[1][nt]);
    }
  }
#pragma unroll
  for (int st = 0; st < 2; ++st) {
    const int mbase = mt * 128 + (2 * w + st) * 16 + q * 4;
#pragma unroll
    for (int nt = 0; nt < 8; ++nt)
#pragma unroll
      for (int r = 0; r < 4; ++r)
        part[(size_t)kc * 524288 + (size_t)(mbase + r) * 128 + nt * 16 + ln] = acc[st][nt][r];
  }
}

// ---------------------------------------------------------------------------
// 1024 blocks x 256 thr, 2 elems each (pairs within E-dim rows)
__global__ void k_emb_reduce(const float* __restrict__ part, const float* __restrict__ b_emb,
                             float* __restrict__ emb, unsigned* __restrict__ embbf) {
  const unsigned pidx = blockIdx.x * 256u + threadIdx.x;  // < 262144 pairs
  const unsigned e0 = (pidx * 2u) & 127u;
  float2 s = ((const float2*)b_emb)[e0 >> 1];
#pragma unroll
  for (int kc = 0; kc < 8; ++kc) {
    float2 v = ((const float2*)(part + (size_t)kc * 524288u))[pidx];
    s.x += v.x; s.y += v.y;
  }
  ((float2*)emb)[pidx] = s;
  embbf[pidx] = pkbf(s.x, s.y);
}

// ---------------------------------------------------------------------------
// gicat: M=4096, N=768 (cols 0..383: GRU-a incl b_ih_a; 384..767: GRU-b incl b_ih_b), K=128
__global__ __launch_bounds__(256) void k_gi_gemm(const unsigned short* __restrict__ embbf,
                                                 const unsigned short* __restrict__ wih,
                                                 const float* __restrict__ b_ih_a,
                                                 const float* __restrict__ b_ih_b,
                                                 float* __restrict__ gi) {
  const int mt = blockIdx.x / 6, nt6 = blockIdx.x % 6, nbase = nt6 * 128;
  const int w = threadIdx.x >> 6, lane = threadIdx.x & 63, q = lane >> 4, ln = lane & 15;
  const f32x4 zero = {0.f, 0.f, 0.f, 0.f};
  f32x4 acc[2][8];
#pragma unroll
  for (int a = 0; a < 2; ++a)
#pragma unroll
    for (int b = 0; b < 8; ++b) acc[a][b] = zero;

#pragma unroll
  for (int kk = 0; kk < 4; ++kk) {
    const int ko = kk * 32 + q * 8;
    short8 a0 = *(const short8*)(embbf + (size_t)(mt * 128 + (2 * w) * 16 + ln) * 128 + ko);
    short8 a1 = *(const short8*)(embbf + (size_t)(mt * 128 + (2 * w + 1) * 16 + ln) * 128 + ko);
#pragma unroll
    for (int nt = 0; nt < 8; ++nt) {
      short8 b = *(const short8*)(wih + (size_t)(nbase + nt * 16 + ln) * 128 + ko);
      acc[0][nt] = MFMA16(a0, b, acc[0][nt]);
      acc[1][nt] = MFMA16(a1, b, acc[1][nt]);
    }
  }
#pragma unroll
  for (int nt = 0; nt < 8; ++nt) {
    const int g = nbase + nt * 16 + ln;
    const float bias = (g < 384) ? b_ih_a[g] : b_ih_b[g - 384];
#pragma unroll
    for (int st = 0; st < 2; ++st) {
      const int mbase = mt * 128 + (2 * w + st) * 16 + q * 4;
#pragma unroll
      for (int r = 0; r < 4; ++r)
        gi[(size_t)(mbase + r) * 768 + g] = acc[st][nt][r] + bias;
    }
  }
}

// ---------------------------------------------------------------------------
// Fused recurrence + attention. 256 blocks x 512 threads, 1 block/CU.
// amdgpu_waves_per_eu(2,2): exactly our 8-wave occupancy -> 256-VGPR budget so
// the 96-VGPR W_hh fragment set stays resident (R2's VGPR=128 rematerialized
// them from global every step). W_beta/w_alpha frags come from LDS per step
// (in-loop barrier blocks hoisting), keeping peak VGPR ~230.
__global__ __launch_bounds__(512) __attribute__((amdgpu_waves_per_eu(2, 2)))
void k_recur(
    const float* __restrict__ gicat, const float* __restrict__ emb,
    const unsigned short* __restrict__ whha, const unsigned short* __restrict__ whhb,
    const unsigned short* __restrict__ wbeta, const unsigned short* __restrict__ walpha,
    const float* __restrict__ b_hh_a, const float* __restrict__ b_hh_b,
    const float* __restrict__ b_beta, const float* __restrict__ b_alpha,
    unsigned short* __restrict__ cbf) {
  const int tid = threadIdx.x, w = tid >> 6, lane = tid & 63, q = lane >> 4, ln = lane & 15;
  const int p = blockIdx.x >> 3, btile = blockIdx.x & 7;
  const int i1 = p, i2 = 63 - p;  // i2 >= i1
  const int kout = w * 16 + ln;

  // double-buffered h (rows padded to 136 shorts) + staged weight tiles
  __shared__ unsigned short hA[2][16 * 136], hB[2][16 * 136];
  __shared__ unsigned short wbeta_s[16384], walpha_s[2048];
  for (int idx = tid; idx < 16 * 136; idx += 512) { hA[0][idx] = 0; hB[0][idx] = 0; }
  for (int idx = tid; idx < 2048; idx += 512)
    ((short8*)wbeta_s)[idx] = ((const short8*)wbeta)[idx];
  if (tid < 256) ((short8*)walpha_s)[tid] = ((const short8*)walpha)[tid];

  int iq_r[4], b_r[4];
#pragma unroll
  for (int r = 0; r < 4; ++r) {
    const int row = q * 4 + r;
    iq_r[r] = (row < 8) ? i1 : i2;
    b_r[r] = btile * 8 + (row & 7);
  }

  // ---- persistent gate B-fragments (96 VGPRs)
  short8 fra[3][4], frb[3][4];
#pragma unroll
  for (int g = 0; g < 3; ++g) {
    const unsigned short* ba = whha + (size_t)(g * 128 + kout) * 128;
    const unsigned short* bb = whhb + (size_t)(g * 128 + kout) * 128;
#pragma unroll
    for (int kc = 0; kc < 4; ++kc) {
      fra[g][kc] = *(const short8*)(ba + kc * 32 + q * 8);
      frb[g][kc] = *(const short8*)(bb + kc * 32 + q * 8);
    }
  }
  float bhA[3], bhB[3];
#pragma unroll
  for (int g = 0; g < 3; ++g) { bhA[g] = b_hh_a[g * 128 + kout]; bhB[g] = b_hh_b[g * 128 + kout]; }
  const float bbet = b_beta[kout];
  const float balpha0 = b_alpha[0];

  float hRA[4], hRB[4], cac[4], lreg[4];
#pragma unroll
  for (int r = 0; r < 4; ++r) { hRA[r] = 0.f; hRB[r] = 0.f; cac[r] = 0.f; lreg[r] = 0.f; }

  const f32x4 zero = {0.f, 0.f, 0.f, 0.f};
  __syncthreads();

  for (int s = 0; s <= i2; ++s) {
    const int rb = s & 1, wb = rb ^ 1;

    // ---- step-top loads: gate inputs + emb value (consumed after MFMA phase)
    float ga[4][3], gb[4][3], embv[4];
#pragma unroll
    for (int r = 0; r < 4; ++r) {
      int j = iq_r[r] - s; j = (j < 0) ? 0 : j;
      const float* gp = gicat + (size_t)(j * 64 + b_r[r]) * 768 + kout;
      ga[r][0] = gp[0];   ga[r][1] = gp[128]; ga[r][2] = gp[256];
      gb[r][0] = gp[384]; gb[r][1] = gp[512]; gb[r][2] = gp[640];
      embv[r] = emb[(size_t)(j * 64 + b_r[r]) * 128 + kout];
    }

    // ---- h_old A-fragments from buf rb
    short8 haf[4], hbf[4];
#pragma unroll
    for (int kc = 0; kc < 4; ++kc) {
      haf[kc] = *(const short8*)(hA[rb] + ln * 136 + kc * 32 + q * 8);
      hbf[kc] = *(const short8*)(hB[rb] + ln * 136 + kc * 32 + q * 8);
    }

    // ---- gate MFMAs (24/wave)
    f32x4 accA[3] = {zero, zero, zero}, accB[3] = {zero, zero, zero};
#pragma unroll
    for (int kc = 0; kc < 4; ++kc)
#pragma unroll
      for (int g = 0; g < 3; ++g) {
        accA[g] = MFMA16(haf[kc], fra[g][kc], accA[g]);
        accB[g] = MFMA16(hbf[kc], frb[g][kc], accB[g]);
      }

    // ---- gate math + h_new -> buf wb
#pragma unroll
    for (int r = 0; r < 4; ++r) {
      const int rowoff = (q * 4 + r) * 136 + kout;
      {
        const float rr = sigm(ga[r][0] + accA[0][r] + bhA[0]);
        const float zz = sigm(ga[r][1] + accA[1][r] + bhA[1]);
        const float nn = tanh_f(ga[r][2] + rr * (accA[2][r] + bhA[2]));
        const float hn = (1.f - zz) * nn + zz * hRA[r];
        hRA[r] = hn;
        hA[wb][rowoff] = f2bf(hn);
      }
      {
        const float rr = sigm(gb[r][0] + accB[0][r] + bhB[0]);
        const float zz = sigm(gb[r][1] + accB[1][r] + bhB[1]);
        const float nn = tanh_f(gb[r][2] + rr * (accB[2][r] + bhB[2]));
        const float hn = (1.f - zz) * nn + zz * hRB[r];
        hRB[r] = hn;
        hB[wb][rowoff] = f2bf(hn);
      }
    }
    __syncthreads();  // the ONLY barrier per step

    // ---- attention: alpha (redundant per wave) + beta on h_new (buf wb)
    short8 hnAf[4], hnBf[4], fbe[4], fal[4];
#pragma unroll
    for (int kc = 0; kc < 4; ++kc) {
      hnAf[kc] = *(const short8*)(hA[wb] + ln * 136 + kc * 32 + q * 8);
      hnBf[kc] = *(const short8*)(hB[wb] + ln * 136 + kc * 32 + q * 8);
      fbe[kc] = *(const short8*)(wbeta_s + (size_t)kout * 128 + kc * 32 + q * 8);
      fal[kc] = *(const short8*)(walpha_s + (size_t)ln * 128 + kc * 32 + q * 8);
    }
    f32x4 accL = zero, accV = zero;
#pragma unroll
    for (int kc = 0; kc < 4; ++kc) {
      accL = MFMA16(hnAf[kc], fal[kc], accL);
      accV = MFMA16(hnBf[kc], fbe[kc], accV);
    }
#pragma unroll
    for (int r = 0; r < 4; ++r) {
      // logit for row q*4+r sits at lane q*16 (col 0), reg r
      const float logit = __shfl(accL[r], lane & 48) + balpha0;
      const float pp = (s <= iq_r[r]) ? __expf(logit) : 0.0f;
      lreg[r] += pp;
      const float beta = tanh_f(accV[r] + bbet);
      cac[r] += pp * beta * embv[r];
    }
  }

  // ---- epilogue: per-wave normalize, no LDS needed
#pragma unroll
  for (int r = 0; r < 4; ++r) {
    const float val = cac[r] / (lreg[r] * (float)(iq_r[r] + 1));
    cbf[(size_t)(iq_r[r] * 64 + b_r[r]) * 128 + kout] = f2bf(val);
  }
}

// ---------------------------------------------------------------------------
// out = sigmoid(c @ W_out.T + b_out): M=4096, N=4096, K=128. 1024 blocks of 128x128.
__global__ __launch_bounds__(256) void k_out_gemm(const unsigned short* __restrict__ cbf,
                                                  const unsigned short* __restrict__ wout,
                                                  const float* __restrict__ b_out,
                                                  float* __restrict__ out) {
  const int mt = blockIdx.x >> 5, nt32 = blockIdx.x & 31, nbase = nt32 * 128;
  const int w = threadIdx.x >> 6, lane = threadIdx.x & 63, q = lane >> 4, ln = lane & 15;
  const f32x4 zero = {0.f, 0.f, 0.f, 0.f};
  f32x4 acc[2][8];
#pragma unroll
  for (int a = 0; a < 2; ++a)
#pragma unroll
    for (int b = 0; b < 8; ++b) acc[a][b] = zero;

#pragma unroll
  for (int kk = 0; kk < 4; ++kk) {
    const int ko = kk * 32 + q * 8;
    short8 a0 = *(const short8*)(cbf + (size_t)(mt * 128 + (2 * w) * 16 + ln) * 128 + ko);
    short8 a1 = *(const short8*)(cbf + (size_t)(mt * 128 + (2 * w + 1) * 16 + ln) * 128 + ko);
#pragma unroll
    for (int nt = 0; nt < 8; ++nt) {
      short8 b = *(const short8*)(wout + (size_t)(nbase + nt * 16 + ln) * 128 + ko);
      acc[0][nt] = MFMA16(a0, b, acc[0][nt]);
      acc[1][nt] = MFMA16(a1, b, acc[1][nt]);
    }
  }
#pragma unroll
  for (int nt = 0; nt < 8; ++nt) {
    const int n = nbase + nt * 16 + ln;
    const float bo = b_out[n];
#pragma unroll
    for (int st = 0; st < 2; ++st) {
      const int mbase = mt * 128 + (2 * w + st) * 16 + q * 4;
#pragma unroll
      for (int r = 0; r < 4; ++r)
        out[(size_t)(mbase + r) * 4096 + n] = sigm(acc[st][nt][r] + bo);
    }
  }
}

// ---------------------------------------------------------------------------
extern "C" void kernel_launch(void* const* d_in, const int* in_sizes, int n_in,
                              void* d_out, int out_size, void* d_ws, size_t ws_size,
                              hipStream_t stream) {
  const float* x      = (const float*)d_in[0];
  const float* W_emb  = (const float*)d_in[1];
  const float* b_emb  = (const float*)d_in[2];
  const float* W_ih_a = (const float*)d_in[3];
  const float* W_hh_a = (const float*)d_in[4];
  const float* b_ih_a = (const float*)d_in[5];
  const float* b_hh_a = (const float*)d_in[6];
  const float* W_ih_b = (const float*)d_in[7];
  const float* W_hh_b = (const float*)d_in[8];
  const float* b_ih_b = (const float*)d_in[9];
  const float* b_hh_b = (const float*)d_in[10];
  const float* w_alpha = (const float*)d_in[11];
  const float* b_alpha = (const float*)d_in[12];
  const float* W_beta = (const float*)d_in[13];
  const float* b_beta = (const float*)d_in[14];
  const float* W_out  = (const float*)d_in[15];
  const float* b_out  = (const float*)d_in[16];
  float* out = (float*)d_out;

  char* ws = (char*)d_ws;
  float*          part   = (float*)(ws + OFF_PART);
  float*          emb    = (float*)(ws + OFF_EMB);
  float*          gicat  = (float*)(ws + OFF_GI);
  unsigned*       embbf  = (unsigned*)(ws + OFF_EMBBF);
  unsigned short* cbf    = (unsigned short*)(ws + OFF_CBF);
  unsigned*       wemb   = (unsigned*)(ws + OFF_WEMB);
  unsigned*       wout   = (unsigned*)(ws + OFF_WOUT);
  unsigned*       whha   = (unsigned*)(ws + OFF_WHHA);
  unsigned*       whhb   = (unsigned*)(ws + OFF_WHHB);
  unsigned*       wih    = (unsigned*)(ws + OFF_WIH);
  unsigned*       wbeta  = (unsigned*)(ws + OFF_WBETA);
  unsigned*       walpha = (unsigned*)(ws + OFF_WALPHA);

  k_prep<<<1024, 256, 0, stream>>>(W_emb, W_out, W_hh_a, W_hh_b, W_ih_a, W_ih_b,
                                   W_beta, w_alpha, wemb, wout, whha, whhb, wih,
                                   wbeta, walpha);
  k_emb_gemm<<<256, 256, 0, stream>>>(x, (const unsigned short*)wemb, part);
  k_emb_reduce<<<1024, 256, 0, stream>>>(part, b_emb, emb, embbf);
  k_gi_gemm<<<192, 256, 0, stream>>>((const unsigned short*)embbf, (const unsigned short*)wih,
                                     b_ih_a, b_ih_b, gicat);
  k_recur<<<256, 512, 0, stream>>>(gicat, emb, (const unsigned short*)whha,
                                   (const unsigned short*)whhb, (const unsigned short*)wbeta,
                                   (const unsigned short*)walpha,
                                   b_hh_a, b_hh_b, b_beta, b_alpha, cbf);
  k_out_gemm<<<1024, 256, 0, stream>>>(cbf, (const unsigned short*)wout, b_out, out);
}